// Round 17
// baseline (91.560 us; speedup 1.0000x reference)
//
#include <hip/hip_runtime.h>

#define N_NODES 50000
#define N_EDGES 800000
#define NBLKA 200                 // Phase-A blocks; 800000/200 = 4000 edges each
#define EPB (N_EDGES / NBLKA)     // 4000
#define NBUCK 196                 // ceil(50000/256) buckets of 256 nodes
#define GEMMBLKS ((N_NODES + 63) / 64)   // 782

typedef unsigned int uint;
typedef unsigned short ushort;

// f32 -> bf16 RTNE pack of two values into one uint
__device__ __forceinline__ uint bf16pack(float a, float b) {
    uint ua = __float_as_uint(a); ua = (ua + 0x7FFFu + ((ua >> 16) & 1u)) >> 16;
    uint ub = __float_as_uint(b); ub = (ub + 0x7FFFu + ((ub >> 16) & 1u)) >> 16;
    return ua | (ub << 16);
}
#define BF_LO(U) __uint_as_float((U) << 16)
#define BF_HI(U) __uint_as_float((U) & 0xFFFF0000u)

// ---------------------------------------------------------------------------
// K1: blocks 0..199 = per-block 256-bin histogram of dst>>8 -> blockcounts
//     blocks 200..224 = wfuse (W12 = W1@W2, bw = b1@W2)
__global__ void histA_wfuse_kernel(const int* __restrict__ dst,
                                   int* __restrict__ blockcounts,
                                   const float* __restrict__ W1, const float* __restrict__ W2,
                                   const float* __restrict__ b1, float* __restrict__ W12,
                                   float* __restrict__ bw) {
    if (blockIdx.x < NBLKA) {
        __shared__ int h[256];
        h[threadIdx.x] = 0;
        __syncthreads();
        const int4* d4 = (const int4*)(dst + blockIdx.x * EPB);
        for (int i = threadIdx.x; i < EPB / 4; i += 256) {
            int4 v = d4[i];
            atomicAdd(&h[v.x >> 8], 1);
            atomicAdd(&h[v.y >> 8], 1);
            atomicAdd(&h[v.z >> 8], 1);
            atomicAdd(&h[v.w >> 8], 1);
        }
        __syncthreads();
        blockcounts[blockIdx.x * 256 + threadIdx.x] = h[threadIdx.x];  // coalesced
    } else {
        int idx = (blockIdx.x - NBLKA) * 256 + threadIdx.x;
        if (idx < 96 * 64) {
            int k = idx >> 6, nn = idx & 63;
            float s = 0.0f;
#pragma unroll
            for (int j = 0; j < 96; ++j) s = fmaf(W1[k * 96 + j], W2[j * 64 + nn], s);
            W12[idx] = s;
        } else if (idx < 96 * 64 + 64) {
            int nn = idx - 96 * 64;
            float s = 0.0f;
#pragma unroll
            for (int j = 0; j < 96; ++j) s = fmaf(b1[j], W2[j * 64 + nn], s);
            bw[nn] = s;
        }
    }
}

// ---------------------------------------------------------------------------
// K2 (1 block): bin totals = column sums of blockcounts (coalesced rows),
// exclusive scan -> basearr[257] (deterministic bucket boundaries) + cursor.
// NOTE (R16 bugfix): basearr is 257 ints = 1028 B; cursor must NOT overlap
// basearr[256] (R15 placed cursor at +1024 -> cursor[0] aliased basearr[256],
// racing bin-0's reservation base against the grand total -> OOB scatter).
__global__ void scanbins_kernel(const int* __restrict__ blockcounts,
                                int* __restrict__ basearr, int* __restrict__ cursor) {
    __shared__ int s[256];
    int t = threadIdx.x;
    int v = 0;
    for (int b = 0; b < NBLKA; ++b) v += blockcounts[b * 256 + t];
    s[t] = v;
    __syncthreads();
    for (int d = 1; d < 256; d <<= 1) {
        int x = (t >= d) ? s[t - d] : 0;
        __syncthreads();
        s[t] += x;
        __syncthreads();
    }
    int excl = s[t] - v;
    basearr[t] = excl;
    cursor[t] = excl;
    if (t == 255) basearr[256] = s[255];
}

// ---------------------------------------------------------------------------
// K3: merged scatter (blocks 0..NBLKA-1) + GEMM (blocks NBLKA..).
// scatter: each block RESERVES its per-bin runs via atomicAdd(cursor) --
// replaces the 51200-entry hierarchical scan.
// gemm: W12 (24KB, broadcast, L1-resident) read directly from global.
#define FMA4(ACC, SCL, WV)                                                     \
    ACC.x = fmaf(SCL, WV.x, ACC.x);                                            \
    ACC.y = fmaf(SCL, WV.y, ACC.y);                                            \
    ACC.z = fmaf(SCL, WV.z, ACC.z);                                            \
    ACC.w = fmaf(SCL, WV.w, ACC.w);

__global__ __launch_bounds__(256)
void scatter_gemm_kernel(const int* __restrict__ src, const int* __restrict__ dst,
                         const int* __restrict__ blockcounts, int* __restrict__ cursor,
                         uint* __restrict__ ebuf,
                         const float* __restrict__ A, const float* __restrict__ W,
                         ushort* __restrict__ y16, int M) {
    __shared__ float smem[64 * 100];   // gemm: sA; scatter: off (aliased)
    int tid = threadIdx.x;

    if (blockIdx.x < NBLKA) {
        int* off = (int*)smem;
        int mc = blockcounts[blockIdx.x * 256 + tid];
        off[tid] = atomicAdd(&cursor[tid], mc);
        __syncthreads();
        int base = blockIdx.x * EPB;
        for (int i = base + tid; i < base + EPB; i += 256) {
            int s = src[i];
            int d = dst[i];
            int p = atomicAdd(&off[d >> 8], 1);
            ebuf[p] = (uint)s | ((uint)(d & 255) << 16);
        }
        return;
    }

    int bid = blockIdx.x - NBLKA;
    float* sA = smem;
    long row0 = (long)bid * 64;
    {   // stage A rows (coalesced float4; clamp for tail block)
        const float4* A4 = (const float4*)A;
        long base4 = row0 * 24;
        long lim = (long)M * 24 - 1;
        for (int f = tid; f < 64 * 24; f += 256) {
            long g = base4 + f;
            if (g > lim) g = lim;
            float4 v = A4[g];
            int r = f / 24, kc = f - r * 24;
            *(float4*)(sA + r * 100 + kc * 4) = v;
        }
    }
    __syncthreads();

    int tx = tid & 15;
    int ty = tid >> 4;
    float4 acc0 = {0, 0, 0, 0};
    float4 acc1 = {0, 0, 0, 0};
    float4 acc2 = {0, 0, 0, 0};
    float4 acc3 = {0, 0, 0, 0};
    const float* pa = sA + ty * 4 * 100;
    const float4* W4 = (const float4*)W;

#pragma unroll 1
    for (int k = 0; k < 96; k += 4) {
        float4 a0 = *(const float4*)(pa + 0 * 100 + k);
        float4 a1 = *(const float4*)(pa + 1 * 100 + k);
        float4 a2 = *(const float4*)(pa + 2 * 100 + k);
        float4 a3 = *(const float4*)(pa + 3 * 100 + k);
        float4 w0 = W4[(k + 0) * 16 + tx];
        float4 w1 = W4[(k + 1) * 16 + tx];
        float4 w2 = W4[(k + 2) * 16 + tx];
        float4 w3 = W4[(k + 3) * 16 + tx];
        FMA4(acc0, a0.x, w0) FMA4(acc0, a0.y, w1) FMA4(acc0, a0.z, w2) FMA4(acc0, a0.w, w3)
        FMA4(acc1, a1.x, w0) FMA4(acc1, a1.y, w1) FMA4(acc1, a1.z, w2) FMA4(acc1, a1.w, w3)
        FMA4(acc2, a2.x, w0) FMA4(acc2, a2.y, w1) FMA4(acc2, a2.z, w2) FMA4(acc2, a2.w, w3)
        FMA4(acc3, a3.x, w0) FMA4(acc3, a3.y, w1) FMA4(acc3, a3.z, w2) FMA4(acc3, a3.w, w3)
    }

    long r0 = row0 + ty * 4;
    uint2 p0 = {bf16pack(acc0.x, acc0.y), bf16pack(acc0.z, acc0.w)};
    uint2 p1 = {bf16pack(acc1.x, acc1.y), bf16pack(acc1.z, acc1.w)};
    uint2 p2 = {bf16pack(acc2.x, acc2.y), bf16pack(acc2.z, acc2.w)};
    uint2 p3 = {bf16pack(acc3.x, acc3.y), bf16pack(acc3.z, acc3.w)};
    if (r0 + 0 < M) *(uint2*)(y16 + (r0 + 0) * 64 + tx * 4) = p0;
    if (r0 + 1 < M) *(uint2*)(y16 + (r0 + 1) * 64 + tx * 4) = p1;
    if (r0 + 2 < M) *(uint2*)(y16 + (r0 + 2) * 64 + tx * 4) = p2;
    if (r0 + 3 < M) *(uint2*)(y16 + (r0 + 3) * 64 + tx * 4) = p3;
}

// ---------------------------------------------------------------------------
// K4: one block per 256-node bucket ([basearr[k], basearr[k+1])). LDS degree
// count -> rowstart + dinv, then LDS-cursor scatter of esrc (ushort ids).
__global__ void bucket_kernel(const uint* __restrict__ ebuf, const int* __restrict__ basearr,
                              int* __restrict__ rowstart, float* __restrict__ dinv,
                              ushort* __restrict__ esrc) {
    __shared__ int cnt[256];
    __shared__ int cur[256];
    __shared__ int s[256];
    int k = blockIdx.x;
    int tid = threadIdx.x;
    int base = basearr[k];
    int end  = basearr[k + 1];
    cnt[tid] = 0;
    __syncthreads();
    for (int i = base + tid; i < end; i += 256)
        atomicAdd(&cnt[(ebuf[i] >> 16) & 255], 1);
    __syncthreads();
    int v = cnt[tid];
    s[tid] = v;
    __syncthreads();
    for (int d = 1; d < 256; d <<= 1) {
        int t = (tid >= d) ? s[tid - d] : 0;
        __syncthreads();
        s[tid] += t;
        __syncthreads();
    }
    int excl = s[tid] - v;
    int node = (k << 8) + tid;
    cur[tid] = base + excl;
    if (node < N_NODES) {
        rowstart[node] = base + excl;
        dinv[node] = rsqrtf((float)v + 1.0f);
    }
    if (k == 0 && tid == 0) rowstart[N_NODES] = N_EDGES;
    __syncthreads();
    for (int i = base + tid; i < end; i += 256) {
        uint e = ebuf[i];
        int p = atomicAdd(&cur[(e >> 16) & 255], 1);
        esrc[p] = (ushort)(e & 0xFFFFu);
    }
}

// ---------------------------------------------------------------------------
// K5/K6: aggregation over bf16 rows, 16 LANES PER NODE (4 nodes/wave).
// Group = 16 lanes: 2 edge-subslots x 8 feature-lanes (uint4 = 8 bf16 each).
// Padded batch lanes carry dj=0 -> contribute 0; f32 accumulation.
#define DECFMA(A0, A1, A2, A3, A4, A5, A6, A7, C, V)                           \
    A0 = fmaf(BF_LO(V.x), C, A0); A1 = fmaf(BF_HI(V.x), C, A1);                \
    A2 = fmaf(BF_LO(V.y), C, A2); A3 = fmaf(BF_HI(V.y), C, A3);                \
    A4 = fmaf(BF_LO(V.z), C, A4); A5 = fmaf(BF_HI(V.z), C, A5);                \
    A6 = fmaf(BF_LO(V.w), C, A6); A7 = fmaf(BF_HI(V.w), C, A7);

template <bool FINAL>
__global__ __launch_bounds__(256)
void agg_kernel(const ushort* __restrict__ yin, const int* __restrict__ rowstart,
                const ushort* __restrict__ esrc, const float* __restrict__ dinv,
                const float* __restrict__ bw, const float* __restrict__ b2,
                ushort* __restrict__ zout, float* __restrict__ fout, int n) {
    int gid = (blockIdx.x * blockDim.x + threadIdx.x) >> 4;   // node id
    int gl = threadIdx.x & 15;                                // lane in group
    if (gid >= n) return;
    int rs = rowstart[gid];
    int re = rowstart[gid + 1];
    float di = dinv[gid];
    int sub = gl >> 3;          // edge subslot 0/1
    int q = gl & 7;             // uint4 feature index
    int wbase = (threadIdx.x & 63) & 48;   // group's base lane within wave
    const uint4* yrow = (const uint4*)yin;
    float P0 = 0, P1 = 0, P2 = 0, P3 = 0, P4 = 0, P5 = 0, P6 = 0, P7 = 0;
    float sd = 0.0f;

    for (int base = rs; base < re; base += 16) {
        int idx = base + gl;
        bool ok = idx < re;
        int sj = ok ? (int)esrc[idx] : 0;
        float dj = ok ? dinv[sj] : 0.0f;
        sd += dj;
        int nn = re - base;
        if (nn > 16) nn = 16;
        for (int it = 0; it * 2 < nn; ++it) {
            int e = it * 2 + sub;
            int sl = wbase + e;
            int s0 = __shfl(sj, sl);
            float c0 = __shfl(dj, sl);
            uint4 v0 = yrow[(long)s0 * 8 + q];
            DECFMA(P0, P1, P2, P3, P4, P5, P6, P7, c0, v0)
        }
    }

    // fold the 2 subslots (bit 3 stays inside the 16-lane group)
    float t0 = P0 + __shfl_xor(P0, 8);
    float t1 = P1 + __shfl_xor(P1, 8);
    float t2 = P2 + __shfl_xor(P2, 8);
    float t3 = P3 + __shfl_xor(P3, 8);
    float t4 = P4 + __shfl_xor(P4, 8);
    float t5 = P5 + __shfl_xor(P5, 8);
    float t6 = P6 + __shfl_xor(P6, 8);
    float t7 = P7 + __shfl_xor(P7, 8);

    // self term
    uint4 sv = yrow[(long)gid * 8 + q];
    float dii = di * di;
    float o0 = fmaf(t0, di, BF_LO(sv.x) * dii);
    float o1 = fmaf(t1, di, BF_HI(sv.x) * dii);
    float o2 = fmaf(t2, di, BF_LO(sv.y) * dii);
    float o3 = fmaf(t3, di, BF_HI(sv.y) * dii);
    float o4 = fmaf(t4, di, BF_LO(sv.z) * dii);
    float o5 = fmaf(t5, di, BF_HI(sv.z) * dii);
    float o6 = fmaf(t6, di, BF_LO(sv.w) * dii);
    float o7 = fmaf(t7, di, BF_HI(sv.w) * dii);

    if (FINAL) {
        // sum dj over all 16 lanes of the group (bits 0..3)
        sd += __shfl_xor(sd, 1); sd += __shfl_xor(sd, 2);
        sd += __shfl_xor(sd, 4); sd += __shfl_xor(sd, 8);
        float si = di * (di + sd);
        int fo = q * 8;
        float4 bwa = *(const float4*)(bw + fo);
        float4 bwb = *(const float4*)(bw + fo + 4);
        float4 b2a = *(const float4*)(b2 + fo);
        float4 b2b = *(const float4*)(b2 + fo + 4);
        o0 = fmaf(si, bwa.x, o0) + b2a.x;
        o1 = fmaf(si, bwa.y, o1) + b2a.y;
        o2 = fmaf(si, bwa.z, o2) + b2a.z;
        o3 = fmaf(si, bwa.w, o3) + b2a.w;
        o4 = fmaf(si, bwb.x, o4) + b2b.x;
        o5 = fmaf(si, bwb.y, o5) + b2b.y;
        o6 = fmaf(si, bwb.z, o6) + b2b.z;
        o7 = fmaf(si, bwb.w, o7) + b2b.w;
        if (sub == 0) {
            float4 wa = {o0, o1, o2, o3};
            float4 wb = {o4, o5, o6, o7};
            *(float4*)(fout + (long)gid * 64 + q * 8) = wa;
            *(float4*)(fout + (long)gid * 64 + q * 8 + 4) = wb;
        }
    } else {
        if (sub == 0) {
            uint4 pk;
            pk.x = bf16pack(o0, o1);
            pk.y = bf16pack(o2, o3);
            pk.z = bf16pack(o4, o5);
            pk.w = bf16pack(o6, o7);
            *(uint4*)(zout + (long)gid * 64 + q * 8) = pk;
        }
    }
}

// ---------------------------------------------------------------------------
extern "C" void kernel_launch(void* const* d_in, const int* in_sizes, int n_in,
                              void* d_out, int out_size, void* d_ws, size_t ws_size,
                              hipStream_t stream) {
    const float* x  = (const float*)d_in[0];
    const int*   ei = (const int*)d_in[1];
    const float* W1 = (const float*)d_in[2];
    const float* b1 = (const float*)d_in[3];
    const float* W2 = (const float*)d_in[4];
    const float* b2 = (const float*)d_in[5];
    float* out = (float*)d_out;

    const int* src = ei;
    const int* dst = ei + N_EDGES;

    // workspace layout (bytes); z16 aliases ebuf region (ebuf dead after K4).
    // R16: cursor moved to 615936 -- basearr needs 1028 B (257 ints); R15's
    // cursor at +1024 aliased basearr[256] (the grand total) -> OOB scatter.
    char* ws = (char*)d_ws;
    float*  dinv        = (float*) (ws + 0);             // 204800
    int*    rowstart    = (int*)   (ws + 204800);        // 204800 (n+1)
    int*    blockcounts = (int*)   (ws + 409600);        // 204800 (200x256)
    int*    basearr     = (int*)   (ws + 614400);        // 1028 (257 ints)
    int*    cursor      = (int*)   (ws + 615936);        // 1024
    float*  W12         = (float*) (ws + 616960);        // 24576
    float*  bw          = (float*) (ws + 641536);        // 512
    ushort* esrc        = (ushort*)(ws + 642048);        // 1600000 -> 2242048
    ushort* y16         = (ushort*)(ws + 2242048);       // 6400000 -> 8642048
    uint*   ebuf        = (uint*)  (ws + 8642048);       // 3200000 -> 11842048
    ushort* z16         = (ushort*)(ws + 8642048);       // 6400000 (aliases ebuf+)

    // K1: per-block histogram (+ wfuse)
    histA_wfuse_kernel<<<NBLKA + 25, 256, 0, stream>>>(dst, blockcounts,
                                                       W1, W2, b1, W12, bw);
    // K2: bin totals -> basearr + cursor (1 block)
    scanbins_kernel<<<1, 256, 0, stream>>>(blockcounts, basearr, cursor);
    // K3: scatter via atomic reservation || gemm y16 = bf16(x @ W12)
    scatter_gemm_kernel<<<NBLKA + GEMMBLKS, 256, 0, stream>>>(
        src, dst, blockcounts, cursor, ebuf, x, W12, y16, N_NODES);
    // K4: per-bucket rowstart + dinv + LDS-cursor scatter of esrc
    bucket_kernel<<<NBUCK, 256, 0, stream>>>(ebuf, basearr, rowstart, dinv, esrc);
    // K5/K6: z16 = N y16 ; out = N z16 + si*bw + b2
    int aggBlocks = (N_NODES * 16 + 255) / 256;   // 16 lanes per node
    agg_kernel<false><<<aggBlocks, 256, 0, stream>>>(y16, rowstart, esrc, dinv,
                                                     bw, b2, z16, out, N_NODES);
    agg_kernel<true><<<aggBlocks, 256, 0, stream>>>(z16, rowstart, esrc, dinv,
                                                    bw, b2, z16, out, N_NODES);
}

// Round 18
// 86.393 us; speedup vs baseline: 1.0598x; 1.0598x over previous
//
#include <hip/hip_runtime.h>

#define N_NODES 50000
#define N_EDGES 800000
#define NBLKA 200                 // Phase-A blocks; 800000/200 = 4000 edges each
#define EPB (N_EDGES / NBLKA)     // 4000
#define NBUCK 196                 // ceil(50000/256) buckets of 256 nodes
#define MSCAN (256 * NBLKA)       // 51200 hist entries to scan
#define GEMMBLKS ((N_NODES + 63) / 64)   // 782

typedef unsigned int uint;
typedef unsigned short ushort;

// f32 -> bf16 RTNE pack of two values into one uint
__device__ __forceinline__ uint bf16pack(float a, float b) {
    uint ua = __float_as_uint(a); ua = (ua + 0x7FFFu + ((ua >> 16) & 1u)) >> 16;
    uint ub = __float_as_uint(b); ub = (ub + 0x7FFFu + ((ub >> 16) & 1u)) >> 16;
    return ua | (ub << 16);
}
#define BF_LO(U) __uint_as_float((U) << 16)
#define BF_HI(U) __uint_as_float((U) & 0xFFFF0000u)

// ---------------------------------------------------------------------------
// Phase A1: per-block 256-bin histogram of dst>>8, bin-major global layout.
__global__ void histA_kernel(const int* __restrict__ dst, int* __restrict__ hist) {
    __shared__ int h[256];
    h[threadIdx.x] = 0;
    __syncthreads();
    const int4* d4 = (const int4*)(dst + blockIdx.x * EPB);
    for (int i = threadIdx.x; i < EPB / 4; i += 256) {
        int4 v = d4[i];
        atomicAdd(&h[v.x >> 8], 1);
        atomicAdd(&h[v.y >> 8], 1);
        atomicAdd(&h[v.z >> 8], 1);
        atomicAdd(&h[v.w >> 8], 1);
    }
    __syncthreads();
    hist[threadIdx.x * NBLKA + blockIdx.x] = h[threadIdx.x];
}

// ---------------------------------------------------------------------------
// scan1: block-local exclusive scan of hist -> scanned (local), bsum per block
// (R17: reverted to the R14 hierarchical-scan CSR build. R15/R16's atomic-
// reservation variant regressed 86.1 -> 91.6us: its 1-block serial column-sum
// [1 of 256 CUs active] plus 200-way same-address cursor atomics cost more
// than the parallel scan they replaced.)
__global__ void scan1_kernel(const int* __restrict__ in, int* __restrict__ out,
                             int* __restrict__ bsum, int n) {
    __shared__ int s[256];
    int i = blockIdx.x * 256 + threadIdx.x;
    int v = (i < n) ? in[i] : 0;
    s[threadIdx.x] = v;
    __syncthreads();
    for (int d = 1; d < 256; d <<= 1) {
        int t = (threadIdx.x >= d) ? s[threadIdx.x - d] : 0;
        __syncthreads();
        s[threadIdx.x] += t;
        __syncthreads();
    }
    if (i < n) out[i] = s[threadIdx.x] - v;
    if (threadIdx.x == 255) bsum[blockIdx.x] = s[255];
}

// scan2 (block 0) + wfuse (blocks 1..25) merged.
__global__ void scan2_wfuse_kernel(int* __restrict__ bsum, int* __restrict__ boff, int nb,
                                   const float* __restrict__ W1, const float* __restrict__ W2,
                                   const float* __restrict__ b1, float* __restrict__ W12,
                                   float* __restrict__ bw) {
    if (blockIdx.x == 0) {
        __shared__ int s[256];
        int t = threadIdx.x;
        int v = (t < nb) ? bsum[t] : 0;
        s[t] = v;
        __syncthreads();
        for (int d = 1; d < 256; d <<= 1) {
            int x = (t >= d) ? s[t - d] : 0;
            __syncthreads();
            s[t] += x;
            __syncthreads();
        }
        if (t < nb) boff[t] = s[t] - v;
        if (t == nb - 1) boff[nb] = s[t];
    } else {
        int idx = (blockIdx.x - 1) * 256 + threadIdx.x;
        if (idx < 96 * 64) {
            int k = idx >> 6, nn = idx & 63;
            float s = 0.0f;
#pragma unroll
            for (int j = 0; j < 96; ++j) s = fmaf(W1[k * 96 + j], W2[j * 64 + nn], s);
            W12[idx] = s;
        } else if (idx < 96 * 64 + 64) {
            int nn = idx - 96 * 64;
            float s = 0.0f;
#pragma unroll
            for (int j = 0; j < 96; ++j) s = fmaf(b1[j], W2[j * 64 + nn], s);
            bw[nn] = s;
        }
    }
}

// ---------------------------------------------------------------------------
// Merged Phase A2 scatter (blocks 0..NBLKA-1) + GEMM (blocks NBLKA..).
// gemm: W12 (24KB, broadcast, L1-resident) read directly from global.
// ebuf entry packed: src(16b) | (dst&255)(8b) -- node ids < 65536.
#define FMA4(ACC, SCL, WV)                                                     \
    ACC.x = fmaf(SCL, WV.x, ACC.x);                                            \
    ACC.y = fmaf(SCL, WV.y, ACC.y);                                            \
    ACC.z = fmaf(SCL, WV.z, ACC.z);                                            \
    ACC.w = fmaf(SCL, WV.w, ACC.w);

__global__ __launch_bounds__(256)
void scatter_gemm_kernel(const int* __restrict__ src, const int* __restrict__ dst,
                         const int* __restrict__ scanned, const int* __restrict__ boff,
                         uint* __restrict__ ebuf,
                         const float* __restrict__ A, const float* __restrict__ W,
                         ushort* __restrict__ y16, int M) {
    __shared__ float smem[64 * 100];   // gemm: sA; scatter: off (aliased)
    int tid = threadIdx.x;

    if (blockIdx.x < NBLKA) {
        int* off = (int*)smem;
        int gi = tid * NBLKA + blockIdx.x;
        off[tid] = scanned[gi] + boff[gi >> 8];
        __syncthreads();
        int base = blockIdx.x * EPB;
        for (int i = base + tid; i < base + EPB; i += 256) {
            int s = src[i];
            int d = dst[i];
            int p = atomicAdd(&off[d >> 8], 1);
            ebuf[p] = (uint)s | ((uint)(d & 255) << 16);
        }
        return;
    }

    int bid = blockIdx.x - NBLKA;
    float* sA = smem;
    long row0 = (long)bid * 64;
    {   // stage A rows (coalesced float4; clamp for tail block)
        const float4* A4 = (const float4*)A;
        long base4 = row0 * 24;
        long lim = (long)M * 24 - 1;
        for (int f = tid; f < 64 * 24; f += 256) {
            long g = base4 + f;
            if (g > lim) g = lim;
            float4 v = A4[g];
            int r = f / 24, kc = f - r * 24;
            *(float4*)(sA + r * 100 + kc * 4) = v;
        }
    }
    __syncthreads();

    int tx = tid & 15;
    int ty = tid >> 4;
    float4 acc0 = {0, 0, 0, 0};
    float4 acc1 = {0, 0, 0, 0};
    float4 acc2 = {0, 0, 0, 0};
    float4 acc3 = {0, 0, 0, 0};
    const float* pa = sA + ty * 4 * 100;
    const float4* W4 = (const float4*)W;

#pragma unroll 1
    for (int k = 0; k < 96; k += 4) {
        float4 a0 = *(const float4*)(pa + 0 * 100 + k);
        float4 a1 = *(const float4*)(pa + 1 * 100 + k);
        float4 a2 = *(const float4*)(pa + 2 * 100 + k);
        float4 a3 = *(const float4*)(pa + 3 * 100 + k);
        float4 w0 = W4[(k + 0) * 16 + tx];
        float4 w1 = W4[(k + 1) * 16 + tx];
        float4 w2 = W4[(k + 2) * 16 + tx];
        float4 w3 = W4[(k + 3) * 16 + tx];
        FMA4(acc0, a0.x, w0) FMA4(acc0, a0.y, w1) FMA4(acc0, a0.z, w2) FMA4(acc0, a0.w, w3)
        FMA4(acc1, a1.x, w0) FMA4(acc1, a1.y, w1) FMA4(acc1, a1.z, w2) FMA4(acc1, a1.w, w3)
        FMA4(acc2, a2.x, w0) FMA4(acc2, a2.y, w1) FMA4(acc2, a2.z, w2) FMA4(acc2, a2.w, w3)
        FMA4(acc3, a3.x, w0) FMA4(acc3, a3.y, w1) FMA4(acc3, a3.z, w2) FMA4(acc3, a3.w, w3)
    }

    long r0 = row0 + ty * 4;
    uint2 p0 = {bf16pack(acc0.x, acc0.y), bf16pack(acc0.z, acc0.w)};
    uint2 p1 = {bf16pack(acc1.x, acc1.y), bf16pack(acc1.z, acc1.w)};
    uint2 p2 = {bf16pack(acc2.x, acc2.y), bf16pack(acc2.z, acc2.w)};
    uint2 p3 = {bf16pack(acc3.x, acc3.y), bf16pack(acc3.z, acc3.w)};
    if (r0 + 0 < M) *(uint2*)(y16 + (r0 + 0) * 64 + tx * 4) = p0;
    if (r0 + 1 < M) *(uint2*)(y16 + (r0 + 1) * 64 + tx * 4) = p1;
    if (r0 + 2 < M) *(uint2*)(y16 + (r0 + 2) * 64 + tx * 4) = p2;
    if (r0 + 3 < M) *(uint2*)(y16 + (r0 + 3) * 64 + tx * 4) = p3;
}

// ---------------------------------------------------------------------------
// Phase B: one block per 256-node bucket. LDS degree count -> rowstart + dinv,
// then LDS-cursor scatter of esrc (ushort src ids; no global atomics).
__global__ void bucket_kernel(const uint* __restrict__ ebuf, const int* __restrict__ scanned,
                              const int* __restrict__ boff, int* __restrict__ rowstart,
                              float* __restrict__ dinv, ushort* __restrict__ esrc) {
    __shared__ int cnt[256];
    __shared__ int cur[256];
    __shared__ int s[256];
    int k = blockIdx.x;
    int tid = threadIdx.x;
    int i0 = k * NBLKA, i1 = (k + 1) * NBLKA;
    int base = scanned[i0] + boff[i0 >> 8];
    int end  = (k == NBUCK - 1) ? N_EDGES : (scanned[i1] + boff[i1 >> 8]);
    cnt[tid] = 0;
    __syncthreads();
    for (int i = base + tid; i < end; i += 256)
        atomicAdd(&cnt[(ebuf[i] >> 16) & 255], 1);
    __syncthreads();
    int v = cnt[tid];
    s[tid] = v;
    __syncthreads();
    for (int d = 1; d < 256; d <<= 1) {
        int t = (tid >= d) ? s[tid - d] : 0;
        __syncthreads();
        s[tid] += t;
        __syncthreads();
    }
    int excl = s[tid] - v;
    int node = (k << 8) + tid;
    cur[tid] = base + excl;
    if (node < N_NODES) {
        rowstart[node] = base + excl;
        dinv[node] = rsqrtf((float)v + 1.0f);
    }
    if (k == 0 && tid == 0) rowstart[N_NODES] = N_EDGES;
    __syncthreads();
    for (int i = base + tid; i < end; i += 256) {
        uint e = ebuf[i];
        int p = atomicAdd(&cur[(e >> 16) & 255], 1);
        esrc[p] = (ushort)(e & 0xFFFFu);
    }
}

// ---------------------------------------------------------------------------
// Aggregation over bf16 rows, 16 LANES PER NODE (4 nodes/wave).
// Group = 16 lanes: 2 edge-subslots x 8 feature-lanes (uint4 = 8 bf16 each).
// Padded batch lanes carry dj=0 -> contribute 0; f32 accumulation.
#define DECFMA(A0, A1, A2, A3, A4, A5, A6, A7, C, V)                           \
    A0 = fmaf(BF_LO(V.x), C, A0); A1 = fmaf(BF_HI(V.x), C, A1);                \
    A2 = fmaf(BF_LO(V.y), C, A2); A3 = fmaf(BF_HI(V.y), C, A3);                \
    A4 = fmaf(BF_LO(V.z), C, A4); A5 = fmaf(BF_HI(V.z), C, A5);                \
    A6 = fmaf(BF_LO(V.w), C, A6); A7 = fmaf(BF_HI(V.w), C, A7);

template <bool FINAL>
__global__ __launch_bounds__(256)
void agg_kernel(const ushort* __restrict__ yin, const int* __restrict__ rowstart,
                const ushort* __restrict__ esrc, const float* __restrict__ dinv,
                const float* __restrict__ bw, const float* __restrict__ b2,
                ushort* __restrict__ zout, float* __restrict__ fout, int n) {
    int gid = (blockIdx.x * blockDim.x + threadIdx.x) >> 4;   // node id
    int gl = threadIdx.x & 15;                                // lane in group
    if (gid >= n) return;
    int rs = rowstart[gid];
    int re = rowstart[gid + 1];
    float di = dinv[gid];
    int sub = gl >> 3;          // edge subslot 0/1
    int q = gl & 7;             // uint4 feature index
    int wbase = (threadIdx.x & 63) & 48;   // group's base lane within wave
    const uint4* yrow = (const uint4*)yin;
    float P0 = 0, P1 = 0, P2 = 0, P3 = 0, P4 = 0, P5 = 0, P6 = 0, P7 = 0;
    float sd = 0.0f;

    for (int base = rs; base < re; base += 16) {
        int idx = base + gl;
        bool ok = idx < re;
        int sj = ok ? (int)esrc[idx] : 0;
        float dj = ok ? dinv[sj] : 0.0f;
        sd += dj;
        int nn = re - base;
        if (nn > 16) nn = 16;
        for (int it = 0; it * 2 < nn; ++it) {
            int e = it * 2 + sub;
            int sl = wbase + e;
            int s0 = __shfl(sj, sl);
            float c0 = __shfl(dj, sl);
            uint4 v0 = yrow[(long)s0 * 8 + q];
            DECFMA(P0, P1, P2, P3, P4, P5, P6, P7, c0, v0)
        }
    }

    // fold the 2 subslots (bit 3 stays inside the 16-lane group)
    float t0 = P0 + __shfl_xor(P0, 8);
    float t1 = P1 + __shfl_xor(P1, 8);
    float t2 = P2 + __shfl_xor(P2, 8);
    float t3 = P3 + __shfl_xor(P3, 8);
    float t4 = P4 + __shfl_xor(P4, 8);
    float t5 = P5 + __shfl_xor(P5, 8);
    float t6 = P6 + __shfl_xor(P6, 8);
    float t7 = P7 + __shfl_xor(P7, 8);

    // self term
    uint4 sv = yrow[(long)gid * 8 + q];
    float dii = di * di;
    float o0 = fmaf(t0, di, BF_LO(sv.x) * dii);
    float o1 = fmaf(t1, di, BF_HI(sv.x) * dii);
    float o2 = fmaf(t2, di, BF_LO(sv.y) * dii);
    float o3 = fmaf(t3, di, BF_HI(sv.y) * dii);
    float o4 = fmaf(t4, di, BF_LO(sv.z) * dii);
    float o5 = fmaf(t5, di, BF_HI(sv.z) * dii);
    float o6 = fmaf(t6, di, BF_LO(sv.w) * dii);
    float o7 = fmaf(t7, di, BF_HI(sv.w) * dii);

    if (FINAL) {
        // sum dj over all 16 lanes of the group (bits 0..3)
        sd += __shfl_xor(sd, 1); sd += __shfl_xor(sd, 2);
        sd += __shfl_xor(sd, 4); sd += __shfl_xor(sd, 8);
        float si = di * (di + sd);
        int fo = q * 8;
        float4 bwa = *(const float4*)(bw + fo);
        float4 bwb = *(const float4*)(bw + fo + 4);
        float4 b2a = *(const float4*)(b2 + fo);
        float4 b2b = *(const float4*)(b2 + fo + 4);
        o0 = fmaf(si, bwa.x, o0) + b2a.x;
        o1 = fmaf(si, bwa.y, o1) + b2a.y;
        o2 = fmaf(si, bwa.z, o2) + b2a.z;
        o3 = fmaf(si, bwa.w, o3) + b2a.w;
        o4 = fmaf(si, bwb.x, o4) + b2b.x;
        o5 = fmaf(si, bwb.y, o5) + b2b.y;
        o6 = fmaf(si, bwb.z, o6) + b2b.z;
        o7 = fmaf(si, bwb.w, o7) + b2b.w;
        if (sub == 0) {
            float4 wa = {o0, o1, o2, o3};
            float4 wb = {o4, o5, o6, o7};
            *(float4*)(fout + (long)gid * 64 + q * 8) = wa;
            *(float4*)(fout + (long)gid * 64 + q * 8 + 4) = wb;
        }
    } else {
        if (sub == 0) {
            uint4 pk;
            pk.x = bf16pack(o0, o1);
            pk.y = bf16pack(o2, o3);
            pk.z = bf16pack(o4, o5);
            pk.w = bf16pack(o6, o7);
            *(uint4*)(zout + (long)gid * 64 + q * 8) = pk;
        }
    }
}

// ---------------------------------------------------------------------------
extern "C" void kernel_launch(void* const* d_in, const int* in_sizes, int n_in,
                              void* d_out, int out_size, void* d_ws, size_t ws_size,
                              hipStream_t stream) {
    const float* x  = (const float*)d_in[0];
    const int*   ei = (const int*)d_in[1];
    const float* W1 = (const float*)d_in[2];
    const float* b1 = (const float*)d_in[3];
    const float* W2 = (const float*)d_in[4];
    const float* b2 = (const float*)d_in[5];
    float* out = (float*)d_out;

    const int* src = ei;
    const int* dst = ei + N_EDGES;

    // workspace layout (bytes); z16 aliases ebuf region (ebuf dead after bucket)
    char* ws = (char*)d_ws;
    float*  dinv     = (float*) (ws + 0);                // 204800
    int*    rowstart = (int*)   (ws + 204800);           // 204800 (n+1)
    int*    hist     = (int*)   (ws + 409600);           // 204800
    int*    scanned  = (int*)   (ws + 614400);           // 204800 (block-local)
    int*    bsum     = (int*)   (ws + 823296);           // 1024
    int*    boff     = (int*)   (ws + 824320);           // 1024
    float*  W12      = (float*) (ws + 825344);           // 24576
    float*  bw       = (float*) (ws + 849920);           // 512
    ushort* esrc     = (ushort*)(ws + 850432);           // 1600000 -> 2450432
    ushort* y16      = (ushort*)(ws + 2450432);          // 6400000 -> 8850432
    uint*   ebuf     = (uint*)  (ws + 8850432);          // 3200000 -> 12050432
    ushort* z16      = (ushort*)(ws + 8850432);          // 6400000 (aliases ebuf+)

    // Phase A: bucket edges by dst>>8 (full-line writes)
    histA_kernel<<<NBLKA, 256, 0, stream>>>(dst, hist);
    scan1_kernel<<<MSCAN / 256, 256, 0, stream>>>(hist, scanned, bsum, MSCAN);
    scan2_wfuse_kernel<<<26, 256, 0, stream>>>(bsum, boff, MSCAN / 256,
                                               W1, W2, b1, W12, bw);
    // scatter (blocks 0..199) || gemm y16 = bf16(x @ W12) (blocks 200..981)
    scatter_gemm_kernel<<<NBLKA + GEMMBLKS, 256, 0, stream>>>(
        src, dst, scanned, boff, ebuf, x, W12, y16, N_NODES);

    // Phase B: per-bucket rowstart + dinv + LDS-cursor scatter of esrc
    bucket_kernel<<<NBUCK, 256, 0, stream>>>(ebuf, scanned, boff, rowstart, dinv, esrc);

    // two aggregation passes: z16 = N y16 ; out = N z16 + si*bw + b2
    int aggBlocks = (N_NODES * 16 + 255) / 256;   // 16 lanes per node
    agg_kernel<false><<<aggBlocks, 256, 0, stream>>>(y16, rowstart, esrc, dinv,
                                                     bw, b2, z16, out, N_NODES);
    agg_kernel<true><<<aggBlocks, 256, 0, stream>>>(z16, rowstart, esrc, dinv,
                                                    bw, b2, z16, out, N_NODES);
}